// Round 5
// baseline (117.714 us; speedup 1.0000x reference)
//
#include <hip/hip_runtime.h>

#define B_ 4
#define T_ 4096
#define E_ 512
#define A_ 64
#define SQSCALE 0.1803368801111204f   // log2(e)/8 : folds softmax scale + exp->exp2

typedef __attribute__((ext_vector_type(8)))  short bf16x8;
typedef __attribute__((ext_vector_type(8)))  unsigned short ushort8;
typedef __attribute__((ext_vector_type(4)))  unsigned int   u32x4;
typedef __attribute__((ext_vector_type(4)))  float f32x4;
typedef __attribute__((ext_vector_type(16))) float f32x16;

__device__ __forceinline__ unsigned short f2bf(float x) {
    union { float f; unsigned int u; } v; v.f = x;
    unsigned int r = v.u + 0x7fffu + ((v.u >> 16) & 1u);
    return (unsigned short)(r >> 16);
}
// packed f32x2 -> bf16x2 (RNE), single VALU op
__device__ __forceinline__ unsigned cvtpk(float a, float b) {
    unsigned r;
    asm("v_cvt_pk_bf16_f32 %0, %1, %2" : "=v"(r) : "v"(a), "v"(b));
    return r;
}
// v_permlane32_swap_b32: a' = [a_lo | b_lo], b' = [a_hi | b_hi] (distinct values only)
__device__ __forceinline__ void pls(unsigned &a, unsigned &b) {
    asm("v_permlane32_swap_b32 %0, %1" : "+v"(a), "+v"(b));
}

// ------------- Kernel 0: W -> Wct bf16 [192][512] (n-major), Q cols pre-scaled
__global__ __launch_bounds__(256) void prep_w(
    const float* __restrict__ Wq, const float* __restrict__ Wk,
    const float* __restrict__ Wv, unsigned short* __restrict__ Wct)
{
    const int id = blockIdx.x * 256 + threadIdx.x;   // 192*128 threads
    const int n = id >> 7;
    const int k4 = (id & 127) << 2;
    const float* W = (n < 64) ? Wq : ((n < 128) ? Wk : Wv);
    const int col = n & 63;
    const float sc = (n < 64) ? SQSCALE : 1.f;
    union { unsigned short s[4]; unsigned long long ll; } u;
    #pragma unroll
    for (int j = 0; j < 4; ++j) u.s[j] = f2bf(W[(k4 + j) * 64 + col] * sc);
    *(unsigned long long*)&Wct[(long)n * 512 + k4] = u.ll;
}

// ------------- Kernel 1: QKV projection via bf16 MFMA -----------------------
// 512 blocks x 512 threads (8 waves). Block = 32 emb rows staged once in LDS
// (bf16). Wave w: row-group rg=w&1 (16 rows), nt-group ng=w>>1 (3 of 12 output
// 16-col tiles). Q/K -> [B*T][64] bf16, V -> Vt [B][64][T] via LDS transpose.
__global__ __launch_bounds__(512, 4) void qkv_proj_kernel(
    const float* __restrict__ emb, const unsigned short* __restrict__ Wct,
    unsigned short* __restrict__ Qo, unsigned short* __restrict__ Ko,
    unsigned short* __restrict__ Vto)
{
    __shared__ unsigned short at[32][536];   // 33.5 KB, stride 536 (2-way max)
    __shared__ unsigned short vt[64][40];    // 5 KB transpose buffer
    const int tid = threadIdx.x;
    const long row0 = (long)blockIdx.x * 32;

    // ---- stage 32x512 emb rows as bf16 ----
    {
        const int r = tid >> 4, c16 = tid & 15;
        const float* __restrict__ src = emb + (row0 + r) * 512;
        #pragma unroll
        for (int j = 0; j < 4; ++j) {
            const int col = j * 128 + c16 * 8;
            const float4 x0 = *(const float4*)(src + col);
            const float4 x1 = *(const float4*)(src + col + 4);
            u32x4 p;
            p[0] = cvtpk(x0.x, x0.y); p[1] = cvtpk(x0.z, x0.w);
            p[2] = cvtpk(x1.x, x1.y); p[3] = cvtpk(x1.z, x1.w);
            *(u32x4*)&at[r][col] = p;
        }
    }
    __syncthreads();

    const int w = tid >> 6, lane = tid & 63;
    const int c = lane & 15, hi = lane >> 4;
    const int rg = w & 1, ng = w >> 1;

    f32x4 acc[3];
    #pragma unroll
    for (int j = 0; j < 3; ++j) acc[j] = (f32x4){0.f, 0.f, 0.f, 0.f};

    #pragma unroll
    for (int ks = 0; ks < 16; ++ks) {
        const bf16x8 af = *(const bf16x8*)&at[rg * 16 + c][ks * 32 + hi * 8];
        #pragma unroll
        for (int j = 0; j < 3; ++j) {
            const int nt = ng * 3 + j;
            const bf16x8 bf_ = *(const bf16x8*)&Wct[(nt * 16 + c) * 512 + ks * 32 + hi * 8];
            acc[j] = __builtin_amdgcn_mfma_f32_16x16x32_bf16(af, bf_, acc[j], 0, 0, 0);
        }
    }

    // D-frag: row = hi*4+r, col = c
    #pragma unroll
    for (int j = 0; j < 3; ++j) {
        const int nt = ng * 3 + j;
        #pragma unroll
        for (int r4 = 0; r4 < 4; ++r4) {
            const long row = row0 + rg * 16 + hi * 4 + r4;
            const unsigned short v = f2bf(acc[j][r4]);
            if (nt < 4)       Qo[row * 64 + nt * 16 + c] = v;
            else if (nt < 8)  Ko[row * 64 + (nt - 4) * 16 + c] = v;
            else              vt[(nt - 8) * 16 + c][rg * 16 + hi * 4 + r4] = v;
        }
    }
    __syncthreads();
    // Vt write: 64 d x 32 t per block
    const int d = tid >> 3, seg = tid & 7;
    const long bb = row0 >> 12, tloc = row0 & 4095;
    *(unsigned long long*)&Vto[(bb * 64 + d) * T_ + tloc + seg * 4] =
        *(const unsigned long long*)&vt[d][seg * 4];
}

// ------------- Kernel 2: causal flash attention, swapped-operand 32x32 MFMA -
// 512 blocks (4 batches x 128 tiles of 32 q-rows, CU-balanced pairing) x
// 8 waves. 8-way in-block split-K, merged in LDS epilogue.
__global__ __launch_bounds__(512, 4) void attn_kernel(
    const unsigned short* __restrict__ Q, const unsigned short* __restrict__ K,
    const unsigned short* __restrict__ Vt, float* __restrict__ out)
{
    __shared__ float accbuf[8][32][64];   // 64 KB split-K merge
    __shared__ float mbuf[8][32], lbuf[8][32];
    __shared__ float scb[8][32];          // per-wave rescale broadcast

    const int tid = threadIdx.x, w = tid >> 6, lane = tid & 63;
    const int c = lane & 31, h = lane >> 5;
    const int b = blockIdx.x & 3;
    const int u = blockIdx.x >> 2;
    const int t = (u < 64) ? (127 - u) : (u - 64);
    const int qb = t << 5;

    const unsigned short* __restrict__ Qb = Q + ((long)b * T_ + qb) * 64;
    const unsigned short* __restrict__ Kb = K + (long)b * T_ * 64;
    const unsigned short* __restrict__ Vb = Vt + (long)b * 64 * T_;

    // Q^T B-frags: B[k=dim][col=q=c]
    bf16x8 qf[4];
    #pragma unroll
    for (int kk = 0; kk < 4; ++kk)
        qf[kk] = *(const bf16x8*)&Qb[(long)c * 64 + kk * 16 + h * 8];

    f32x16 acc[2];
    #pragma unroll
    for (int ct = 0; ct < 2; ++ct)
        #pragma unroll
        for (int j = 0; j < 16; ++j) acc[ct][j] = 0.f;
    float m = -1e30f, l = 0.f;

    const int nc = ((qb + 31) >> 6) + 1;

    bf16x8 kf[2][4];
    {
        const long s0p = (long)((w < nc) ? w : (nc - 1)) << 6;
        #pragma unroll
        for (int f = 0; f < 2; ++f)
            #pragma unroll
            for (int kk = 0; kk < 4; ++kk)
                kf[f][kk] = *(const bf16x8*)&Kb[(s0p + f * 32 + c) * 64 + kk * 16 + h * 8];
    }

    for (int ci = w; ci < nc; ci += 8) {
        const long s0 = (long)ci << 6;

        bf16x8 vf[4][2];
        #pragma unroll
        for (int ks = 0; ks < 4; ++ks)
            #pragma unroll
            for (int ct = 0; ct < 2; ++ct)
                vf[ks][ct] = *(const bf16x8*)&Vb[(long)(ct * 32 + c) * T_ + s0 + ks * 16 + h * 8];

        // S^T = K Q^T : D[row=key][col=q]
        f32x16 sf[2];
        #pragma unroll
        for (int f = 0; f < 2; ++f) {
            #pragma unroll
            for (int j = 0; j < 16; ++j) sf[f][j] = 0.f;
            #pragma unroll
            for (int kk = 0; kk < 4; ++kk)
                sf[f] = __builtin_amdgcn_mfma_f32_32x32x16_bf16(kf[f][kk], qf[kk], sf[f], 0, 0, 0);
        }

        // prefetch next chunk's K
        bf16x8 kn[2][4];
        {
            const int cin = ci + 8;
            const long s0n = (long)((cin < nc) ? cin : (nc - 1)) << 6;
            #pragma unroll
            for (int f = 0; f < 2; ++f)
                #pragma unroll
                for (int kk = 0; kk < 4; ++kk)
                    kn[f][kk] = *(const bf16x8*)&Kb[(s0n + f * 32 + c) * 64 + kk * 16 + h * 8];
        }

        // causal mask: key = s0 + 32f + (r&3) + 8*(r>>2) + 4h ; q = qb + c
        if ((int)s0 + 63 > qb) {
            #pragma unroll
            for (int f = 0; f < 2; ++f)
                #pragma unroll
                for (int r = 0; r < 16; ++r) {
                    const int key = (int)s0 + f * 32 + ((r & 3) + 8 * (r >> 2)) + 4 * h;
                    if (key > qb + c) sf[f][r] = -1e30f;
                }
        }

        // ---- online softmax (exp2 domain) ----
        float pm = sf[0][0];
        #pragma unroll
        for (int f = 0; f < 2; ++f)
            #pragma unroll
            for (int r = 0; r < 16; ++r) pm = fmaxf(pm, sf[f][r]);
        pm = fmaxf(pm, __shfl_xor(pm, 32));

        float mn = m;
        if (__any(pm > m)) {               // exact skip: if no column grew, sc == 1
            mn = fmaxf(m, pm);
            const float sc = exp2f(m - mn);
            m = mn;
            l *= sc;
            if (h == 0) scb[w][c] = sc;
            asm volatile("s_waitcnt lgkmcnt(0)" ::: "memory");
            __builtin_amdgcn_sched_barrier(0);
            float scr[16];
            #pragma unroll
            for (int r = 0; r < 16; ++r)
                scr[r] = scb[w][((r & 3) + 8 * (r >> 2)) + 4 * h];
            #pragma unroll
            for (int ct = 0; ct < 2; ++ct)
                #pragma unroll
                for (int r = 0; r < 16; ++r) acc[ct][r] *= scr[r];
        }

        float rs = 0.f;
        #pragma unroll
        for (int f = 0; f < 2; ++f)
            #pragma unroll
            for (int r = 0; r < 16; ++r) {
                const float p = exp2f(sf[f][r] - mn);
                sf[f][r] = p;
                rs += p;
            }
        rs += __shfl_xor(rs, 32);
        l += rs;

        // ---- P -> bf16 A-frags via cvt_pk + permlane32_swap; then PV ----
        #pragma unroll
        for (int f = 0; f < 2; ++f) {
            unsigned w01 = cvtpk(sf[f][0], sf[f][1]);
            unsigned w23 = cvtpk(sf[f][2], sf[f][3]);
            unsigned w45 = cvtpk(sf[f][4], sf[f][5]);
            unsigned w67 = cvtpk(sf[f][6], sf[f][7]);
            pls(w01, w45); pls(w23, w67);
            union { unsigned uu[4]; bf16x8 v; } pa0, pa1;
            pa0.uu[0] = w01; pa0.uu[1] = w23; pa0.uu[2] = w45; pa0.uu[3] = w67;
            unsigned x01 = cvtpk(sf[f][8],  sf[f][9]);
            unsigned x23 = cvtpk(sf[f][10], sf[f][11]);
            unsigned x45 = cvtpk(sf[f][12], sf[f][13]);
            unsigned x67 = cvtpk(sf[f][14], sf[f][15]);
            pls(x01, x45); pls(x23, x67);
            pa1.uu[0] = x01; pa1.uu[1] = x23; pa1.uu[2] = x45; pa1.uu[3] = x67;
            #pragma unroll
            for (int ct = 0; ct < 2; ++ct) {
                acc[ct] = __builtin_amdgcn_mfma_f32_32x32x16_bf16(pa0.v, vf[2 * f][ct],     acc[ct], 0, 0, 0);
                acc[ct] = __builtin_amdgcn_mfma_f32_32x32x16_bf16(pa1.v, vf[2 * f + 1][ct], acc[ct], 0, 0, 0);
            }
        }

        #pragma unroll
        for (int f = 0; f < 2; ++f)
            #pragma unroll
            for (int kk = 0; kk < 4; ++kk) kf[f][kk] = kn[f][kk];
    }

    // ---- split-K merge across the 8 waves ----
    if (h == 0) { mbuf[w][c] = m; lbuf[w][c] = l; }
    #pragma unroll
    for (int ct = 0; ct < 2; ++ct)
        #pragma unroll
        for (int r = 0; r < 16; ++r)
            accbuf[w][((r & 3) + 8 * (r >> 2)) + 4 * h][ct * 32 + c] = acc[ct][r];
    __syncthreads();
    #pragma unroll
    for (int i = 0; i < 4; ++i) {
        const int e = tid + i * 512;
        const int q = e >> 6, d = e & 63;
        float ms = mbuf[0][q];
        #pragma unroll
        for (int wv = 1; wv < 8; ++wv) ms = fmaxf(ms, mbuf[wv][q]);
        float ls = 0.f, os = 0.f;
        #pragma unroll
        for (int wv = 0; wv < 8; ++wv) {
            const float e_ = exp2f(mbuf[wv][q] - ms);
            ls += lbuf[wv][q] * e_;
            os += accbuf[wv][q][d] * e_;
        }
        out[((long)b * T_ + qb + q) * 64 + d] = os / ls;
    }
}

extern "C" void kernel_launch(void* const* d_in, const int* in_sizes, int n_in,
                              void* d_out, int out_size, void* d_ws, size_t ws_size,
                              hipStream_t stream)
{
    const float* emb = (const float*)d_in[0];
    const float* Wq  = (const float*)d_in[1];
    const float* Wk  = (const float*)d_in[2];
    const float* Wv  = (const float*)d_in[3];
    float* out = (float*)d_out;

    unsigned short* Qs  = (unsigned short*)d_ws;
    unsigned short* Ks  = Qs + (size_t)B_ * T_ * A_;
    unsigned short* Vs  = Ks + (size_t)B_ * T_ * A_;
    unsigned short* Wct = Vs + (size_t)B_ * T_ * A_;

    prep_w<<<dim3(96), dim3(256), 0, stream>>>(Wq, Wk, Wv, Wct);
    qkv_proj_kernel<<<dim3(512), dim3(512), 0, stream>>>(emb, Wct, Qs, Ks, Vs);
    attn_kernel<<<dim3(512), dim3(512), 0, stream>>>(Qs, Ks, Vs, out);
}

// Round 6
// 88.776 us; speedup vs baseline: 1.3260x; 1.3260x over previous
//
#include <hip/hip_runtime.h>

#define B_ 4
#define T_ 4096
#define E_ 512
#define A_ 64
#define SQSCALE 0.1803368801111204f   // log2(e)/8 : folds softmax scale + exp->exp2

typedef __attribute__((ext_vector_type(8)))  short bf16x8;
typedef __attribute__((ext_vector_type(8)))  unsigned short ushort8;
typedef __attribute__((ext_vector_type(4)))  unsigned int   u32x4;
typedef __attribute__((ext_vector_type(4)))  float f32x4;
typedef __attribute__((ext_vector_type(16))) float f32x16;

__device__ __forceinline__ unsigned short f2bf(float x) {
    union { float f; unsigned int u; } v; v.f = x;
    unsigned int r = v.u + 0x7fffu + ((v.u >> 16) & 1u);
    return (unsigned short)(r >> 16);
}
// packed f32x2 -> bf16x2 (RNE), single VALU op
__device__ __forceinline__ unsigned cvtpk(float a, float b) {
    unsigned r;
    asm("v_cvt_pk_bf16_f32 %0, %1, %2" : "=v"(r) : "v"(a), "v"(b));
    return r;
}
// v_permlane32_swap_b32: a' = [a_lo | b_lo], b' = [a_hi | b_hi] (distinct values only)
__device__ __forceinline__ void pls(unsigned &a, unsigned &b) {
    asm("v_permlane32_swap_b32 %0, %1" : "+v"(a), "+v"(b));
}

// ------------- Kernel 0: W -> Wct bf16 [192][512] (n-major), Q cols pre-scaled
__global__ __launch_bounds__(256) void prep_w(
    const float* __restrict__ Wq, const float* __restrict__ Wk,
    const float* __restrict__ Wv, unsigned short* __restrict__ Wct)
{
    const int id = blockIdx.x * 256 + threadIdx.x;   // 192*128 threads
    const int n = id >> 7;
    const int k4 = (id & 127) << 2;
    const float* W = (n < 64) ? Wq : ((n < 128) ? Wk : Wv);
    const int col = n & 63;
    const float sc = (n < 64) ? SQSCALE : 1.f;
    union { unsigned short s[4]; unsigned long long ll; } u;
    #pragma unroll
    for (int j = 0; j < 4; ++j) u.s[j] = f2bf(W[(k4 + j) * 64 + col] * sc);
    *(unsigned long long*)&Wct[(long)n * 512 + k4] = u.ll;
}

// ------------- Kernel 1: QKV projection via bf16 MFMA -----------------------
// 512 blocks x 512 threads (8 waves). Block = 32 emb rows staged once in LDS
// (bf16). Wave w: row-group rg=w&1 (16 rows), nt-group ng=w>>1 (3 of 12 output
// 16-col tiles). Q/K -> [B*T][64] bf16, V -> Vt [B][64][T] via LDS transpose.
__global__ __launch_bounds__(512, 4) void qkv_proj_kernel(
    const float* __restrict__ emb, const unsigned short* __restrict__ Wct,
    unsigned short* __restrict__ Qo, unsigned short* __restrict__ Ko,
    unsigned short* __restrict__ Vto)
{
    __shared__ unsigned short at[32][536];   // 33.5 KB, stride 536 (2-way max)
    __shared__ unsigned short vt[64][40];    // 5 KB transpose buffer
    const int tid = threadIdx.x;
    const long row0 = (long)blockIdx.x * 32;

    // ---- stage 32x512 emb rows as bf16 ----
    {
        const int r = tid >> 4, c16 = tid & 15;
        const float* __restrict__ src = emb + (row0 + r) * 512;
        #pragma unroll
        for (int j = 0; j < 4; ++j) {
            const int col = j * 128 + c16 * 8;
            const float4 x0 = *(const float4*)(src + col);
            const float4 x1 = *(const float4*)(src + col + 4);
            u32x4 p;
            p[0] = cvtpk(x0.x, x0.y); p[1] = cvtpk(x0.z, x0.w);
            p[2] = cvtpk(x1.x, x1.y); p[3] = cvtpk(x1.z, x1.w);
            *(u32x4*)&at[r][col] = p;
        }
    }
    __syncthreads();

    const int w = tid >> 6, lane = tid & 63;
    const int c = lane & 15, hi = lane >> 4;
    const int rg = w & 1, ng = w >> 1;

    f32x4 acc[3];
    #pragma unroll
    for (int j = 0; j < 3; ++j) acc[j] = (f32x4){0.f, 0.f, 0.f, 0.f};

    #pragma unroll
    for (int ks = 0; ks < 16; ++ks) {
        const bf16x8 af = *(const bf16x8*)&at[rg * 16 + c][ks * 32 + hi * 8];
        #pragma unroll
        for (int j = 0; j < 3; ++j) {
            const int nt = ng * 3 + j;
            const bf16x8 bf_ = *(const bf16x8*)&Wct[(nt * 16 + c) * 512 + ks * 32 + hi * 8];
            acc[j] = __builtin_amdgcn_mfma_f32_16x16x32_bf16(af, bf_, acc[j], 0, 0, 0);
        }
    }

    // D-frag: row = hi*4+r, col = c
    #pragma unroll
    for (int j = 0; j < 3; ++j) {
        const int nt = ng * 3 + j;
        #pragma unroll
        for (int r4 = 0; r4 < 4; ++r4) {
            const long row = row0 + rg * 16 + hi * 4 + r4;
            const unsigned short v = f2bf(acc[j][r4]);
            if (nt < 4)       Qo[row * 64 + nt * 16 + c] = v;
            else if (nt < 8)  Ko[row * 64 + (nt - 4) * 16 + c] = v;
            else              vt[(nt - 8) * 16 + c][rg * 16 + hi * 4 + r4] = v;
        }
    }
    __syncthreads();
    // Vt write: 64 d x 32 t per block
    const int d = tid >> 3, seg = tid & 7;
    const long bb = row0 >> 12, tloc = row0 & 4095;
    *(unsigned long long*)&Vto[(bb * 64 + d) * T_ + tloc + seg * 4] =
        *(const unsigned long long*)&vt[d][seg * 4];
}

// ------------- Kernel 2: causal flash attention, swapped-operand 32x32 MFMA -
// 512 blocks (4 batches x 128 tiles of 32 q-rows, CU-balanced pairing) x
// 8 waves. 8-way in-block split-K, merged in LDS epilogue.
// launch_bounds (512,2): per-thread state needs ~100 VGPRs; (512,4) forced a
// 128 cap -> spills -> 154 MB scratch HBM writes (R5 regression).
__global__ __launch_bounds__(512, 2) void attn_kernel(
    const unsigned short* __restrict__ Q, const unsigned short* __restrict__ K,
    const unsigned short* __restrict__ Vt, float* __restrict__ out)
{
    __shared__ float accbuf[8][32][64];   // 64 KB split-K merge
    __shared__ float mbuf[8][32], lbuf[8][32];
    __shared__ float scb[8][32];          // per-wave rescale broadcast

    const int tid = threadIdx.x, w = tid >> 6, lane = tid & 63;
    const int c = lane & 31, h = lane >> 5;
    const int b = blockIdx.x & 3;
    const int u = blockIdx.x >> 2;
    const int t = (u < 64) ? (127 - u) : (u - 64);
    const int qb = t << 5;

    const unsigned short* __restrict__ Qb = Q + ((long)b * T_ + qb) * 64;
    const unsigned short* __restrict__ Kb = K + (long)b * T_ * 64;
    const unsigned short* __restrict__ Vb = Vt + (long)b * 64 * T_;

    // Q^T B-frags: B[k=dim][col=q=c]
    bf16x8 qf[4];
    #pragma unroll
    for (int kk = 0; kk < 4; ++kk)
        qf[kk] = *(const bf16x8*)&Qb[(long)c * 64 + kk * 16 + h * 8];

    f32x16 acc[2];
    #pragma unroll
    for (int ct = 0; ct < 2; ++ct)
        #pragma unroll
        for (int j = 0; j < 16; ++j) acc[ct][j] = 0.f;
    float m = -1e30f, l = 0.f;

    const int nc = ((qb + 31) >> 6) + 1;

    bf16x8 kf[2][4];
    {
        const long s0p = (long)((w < nc) ? w : (nc - 1)) << 6;
        #pragma unroll
        for (int f = 0; f < 2; ++f)
            #pragma unroll
            for (int kk = 0; kk < 4; ++kk)
                kf[f][kk] = *(const bf16x8*)&Kb[(s0p + f * 32 + c) * 64 + kk * 16 + h * 8];
    }

    for (int ci = w; ci < nc; ci += 8) {
        const long s0 = (long)ci << 6;

        bf16x8 vf[4][2];
        #pragma unroll
        for (int ks = 0; ks < 4; ++ks)
            #pragma unroll
            for (int ct = 0; ct < 2; ++ct)
                vf[ks][ct] = *(const bf16x8*)&Vb[(long)(ct * 32 + c) * T_ + s0 + ks * 16 + h * 8];

        // S^T = K Q^T : D[row=key][col=q]
        f32x16 sf[2];
        #pragma unroll
        for (int f = 0; f < 2; ++f) {
            #pragma unroll
            for (int j = 0; j < 16; ++j) sf[f][j] = 0.f;
            #pragma unroll
            for (int kk = 0; kk < 4; ++kk)
                sf[f] = __builtin_amdgcn_mfma_f32_32x32x16_bf16(kf[f][kk], qf[kk], sf[f], 0, 0, 0);
        }

        // prefetch next chunk's K
        bf16x8 kn[2][4];
        {
            const int cin = ci + 8;
            const long s0n = (long)((cin < nc) ? cin : (nc - 1)) << 6;
            #pragma unroll
            for (int f = 0; f < 2; ++f)
                #pragma unroll
                for (int kk = 0; kk < 4; ++kk)
                    kn[f][kk] = *(const bf16x8*)&Kb[(s0n + f * 32 + c) * 64 + kk * 16 + h * 8];
        }

        // causal mask: key = s0 + 32f + (r&3) + 8*(r>>2) + 4h ; q = qb + c
        if ((int)s0 + 63 > qb) {
            #pragma unroll
            for (int f = 0; f < 2; ++f)
                #pragma unroll
                for (int r = 0; r < 16; ++r) {
                    const int key = (int)s0 + f * 32 + ((r & 3) + 8 * (r >> 2)) + 4 * h;
                    if (key > qb + c) sf[f][r] = -1e30f;
                }
        }

        // ---- online softmax (exp2 domain) ----
        float pm = sf[0][0];
        #pragma unroll
        for (int f = 0; f < 2; ++f)
            #pragma unroll
            for (int r = 0; r < 16; ++r) pm = fmaxf(pm, sf[f][r]);
        pm = fmaxf(pm, __shfl_xor(pm, 32));

        float mn = m;
        if (__any(pm > m)) {               // exact skip: if no column grew, sc == 1
            mn = fmaxf(m, pm);
            const float sc = exp2f(m - mn);
            m = mn;
            l *= sc;
            if (h == 0) scb[w][c] = sc;
            asm volatile("s_waitcnt lgkmcnt(0)" ::: "memory");
            __builtin_amdgcn_sched_barrier(0);
            float scr[16];
            #pragma unroll
            for (int r = 0; r < 16; ++r)
                scr[r] = scb[w][((r & 3) + 8 * (r >> 2)) + 4 * h];
            #pragma unroll
            for (int ct = 0; ct < 2; ++ct)
                #pragma unroll
                for (int r = 0; r < 16; ++r) acc[ct][r] *= scr[r];
        }

        float rs = 0.f;
        #pragma unroll
        for (int f = 0; f < 2; ++f)
            #pragma unroll
            for (int r = 0; r < 16; ++r) {
                const float p = exp2f(sf[f][r] - mn);
                sf[f][r] = p;
                rs += p;
            }
        rs += __shfl_xor(rs, 32);
        l += rs;

        // ---- P -> bf16 A-frags via cvt_pk + permlane32_swap; then PV ----
        #pragma unroll
        for (int f = 0; f < 2; ++f) {
            unsigned w01 = cvtpk(sf[f][0], sf[f][1]);
            unsigned w23 = cvtpk(sf[f][2], sf[f][3]);
            unsigned w45 = cvtpk(sf[f][4], sf[f][5]);
            unsigned w67 = cvtpk(sf[f][6], sf[f][7]);
            pls(w01, w45); pls(w23, w67);
            union { unsigned uu[4]; bf16x8 v; } pa0, pa1;
            pa0.uu[0] = w01; pa0.uu[1] = w23; pa0.uu[2] = w45; pa0.uu[3] = w67;
            unsigned x01 = cvtpk(sf[f][8],  sf[f][9]);
            unsigned x23 = cvtpk(sf[f][10], sf[f][11]);
            unsigned x45 = cvtpk(sf[f][12], sf[f][13]);
            unsigned x67 = cvtpk(sf[f][14], sf[f][15]);
            pls(x01, x45); pls(x23, x67);
            pa1.uu[0] = x01; pa1.uu[1] = x23; pa1.uu[2] = x45; pa1.uu[3] = x67;
            #pragma unroll
            for (int ct = 0; ct < 2; ++ct) {
                acc[ct] = __builtin_amdgcn_mfma_f32_32x32x16_bf16(pa0.v, vf[2 * f][ct],     acc[ct], 0, 0, 0);
                acc[ct] = __builtin_amdgcn_mfma_f32_32x32x16_bf16(pa1.v, vf[2 * f + 1][ct], acc[ct], 0, 0, 0);
            }
        }

        #pragma unroll
        for (int f = 0; f < 2; ++f)
            #pragma unroll
            for (int kk = 0; kk < 4; ++kk) kf[f][kk] = kn[f][kk];
    }

    // ---- split-K merge across the 8 waves ----
    if (h == 0) { mbuf[w][c] = m; lbuf[w][c] = l; }
    #pragma unroll
    for (int ct = 0; ct < 2; ++ct)
        #pragma unroll
        for (int r = 0; r < 16; ++r)
            accbuf[w][((r & 3) + 8 * (r >> 2)) + 4 * h][ct * 32 + c] = acc[ct][r];
    __syncthreads();
    #pragma unroll
    for (int i = 0; i < 4; ++i) {
        const int e = tid + i * 512;
        const int q = e >> 6, d = e & 63;
        float ms = mbuf[0][q];
        #pragma unroll
        for (int wv = 1; wv < 8; ++wv) ms = fmaxf(ms, mbuf[wv][q]);
        float ls = 0.f, os = 0.f;
        #pragma unroll
        for (int wv = 0; wv < 8; ++wv) {
            const float e_ = exp2f(mbuf[wv][q] - ms);
            ls += lbuf[wv][q] * e_;
            os += accbuf[wv][q][d] * e_;
        }
        out[((long)b * T_ + qb + q) * 64 + d] = os / ls;
    }
}

extern "C" void kernel_launch(void* const* d_in, const int* in_sizes, int n_in,
                              void* d_out, int out_size, void* d_ws, size_t ws_size,
                              hipStream_t stream)
{
    const float* emb = (const float*)d_in[0];
    const float* Wq  = (const float*)d_in[1];
    const float* Wk  = (const float*)d_in[2];
    const float* Wv  = (const float*)d_in[3];
    float* out = (float*)d_out;

    unsigned short* Qs  = (unsigned short*)d_ws;
    unsigned short* Ks  = Qs + (size_t)B_ * T_ * A_;
    unsigned short* Vs  = Ks + (size_t)B_ * T_ * A_;
    unsigned short* Wct = Vs + (size_t)B_ * T_ * A_;

    prep_w<<<dim3(96), dim3(256), 0, stream>>>(Wq, Wk, Wv, Wct);
    qkv_proj_kernel<<<dim3(512), dim3(512), 0, stream>>>(emb, Wct, Qs, Ks, Vs);
    attn_kernel<<<dim3(512), dim3(512), 0, stream>>>(Qs, Ks, Vs, out);
}

// Round 7
// 51.749 us; speedup vs baseline: 2.2747x; 1.7155x over previous
//
#include <hip/hip_runtime.h>

#define B_ 4
#define T_ 4096
#define E_ 512
#define A_ 64
#define SQSCALE 0.1803368801111204f   // log2(e)/8 : folds softmax scale + exp->exp2

typedef __attribute__((ext_vector_type(8)))  short bf16x8;
typedef __attribute__((ext_vector_type(8)))  unsigned short ushort8;
typedef __attribute__((ext_vector_type(4)))  unsigned int   u32x4;
typedef __attribute__((ext_vector_type(4)))  float f32x4;
typedef __attribute__((ext_vector_type(16))) float f32x16;

__device__ __forceinline__ unsigned short f2bf(float x) {
    union { float f; unsigned int u; } v; v.f = x;
    unsigned int r = v.u + 0x7fffu + ((v.u >> 16) & 1u);
    return (unsigned short)(r >> 16);
}
__device__ __forceinline__ unsigned cvtpk(float a, float b) {
    unsigned r;
    asm("v_cvt_pk_bf16_f32 %0, %1, %2" : "=v"(r) : "v"(a), "v"(b));
    return r;
}
// v_permlane32_swap_b32 (distinct values only)
__device__ __forceinline__ void pls(unsigned &a, unsigned &b) {
    asm("v_permlane32_swap_b32 %0, %1" : "+v"(a), "+v"(b));
}

// ---- Kernel 0: W -> Wp, fragment-packed bf16 B-frags [nt 12][ks 16][lane 64]x8
// Entry (nt,ks,l): col = nt*16 + (l&15), k = ks*32 + (l>>4)*8 .. +8. Q pre-scaled.
__global__ __launch_bounds__(256) void prep_w(
    const float* __restrict__ Wq, const float* __restrict__ Wk,
    const float* __restrict__ Wv, unsigned short* __restrict__ Wp)
{
    const int e = blockIdx.x * 256 + threadIdx.x;   // 48*256 = 12288 entries
    const int nt = e >> 10;
    const int ks = (e >> 6) & 15;
    const int l  = e & 63;
    const int col = nt * 16 + (l & 15);
    const int kb  = ks * 32 + (l >> 4) * 8;
    const float* W = (col < 64) ? Wq : ((col < 128) ? Wk : Wv);
    const int cc = col & 63;
    const float sc = (col < 64) ? SQSCALE : 1.f;
    union { unsigned short s[8]; ushort8 v; } u;
    #pragma unroll
    for (int j = 0; j < 8; ++j) u.s[j] = f2bf(W[(kb + j) * 64 + cc] * sc);
    *(ushort8*)&Wp[(size_t)e * 8] = u.v;
}

// ---- Kernel 1: QKV projection via bf16 MFMA; outputs fragment-packed K/V ----
// 512 blocks x 512 threads. Block = 32 emb rows. Q -> row-major [B*T][64];
// K -> Kp[b][ci][f][kk][lane]x16B (attn A-frags); V -> Vp[b][ci][ks][ct][lane]x16B
// (attn B-frags). All hot attn loads become lane-linear 1KB transactions.
__global__ __launch_bounds__(512, 4) void qkv_proj_kernel(
    const float* __restrict__ emb, const unsigned short* __restrict__ Wp,
    unsigned short* __restrict__ Qo, unsigned short* __restrict__ Kp,
    unsigned short* __restrict__ Vp)
{
    __shared__ unsigned short at[32][536];   // 33.5 KB, stride 16x67 B (uniform banks)
    __shared__ unsigned short kt[32][72];    // 4.6 KB  [key][dim]
    __shared__ unsigned short vt[64][40];    // 5.1 KB  [dim][key]
    const int tid = threadIdx.x;
    const long row0 = (long)blockIdx.x * 32;

    // stage 32x512 emb rows as bf16 (coalesced float4 reads)
    {
        const int r = tid >> 4, c16 = tid & 15;
        const float* __restrict__ src = emb + (row0 + r) * 512;
        #pragma unroll
        for (int j = 0; j < 4; ++j) {
            const int col = j * 128 + c16 * 8;
            const float4 x0 = *(const float4*)(src + col);
            const float4 x1 = *(const float4*)(src + col + 4);
            u32x4 p;
            p[0] = cvtpk(x0.x, x0.y); p[1] = cvtpk(x0.z, x0.w);
            p[2] = cvtpk(x1.x, x1.y); p[3] = cvtpk(x1.z, x1.w);
            *(u32x4*)&at[r][col] = p;
        }
    }
    __syncthreads();

    const int w = tid >> 6, lane = tid & 63;
    const int c = lane & 15, hi = lane >> 4;
    const int rg = w & 1, ng = w >> 1;

    f32x4 acc[3];
    #pragma unroll
    for (int j = 0; j < 3; ++j) acc[j] = (f32x4){0.f, 0.f, 0.f, 0.f};

    #pragma unroll
    for (int ks = 0; ks < 16; ++ks) {
        const bf16x8 af = *(const bf16x8*)&at[rg * 16 + c][ks * 32 + hi * 8];
        #pragma unroll
        for (int j = 0; j < 3; ++j) {
            const int nt = ng * 3 + j;
            const bf16x8 bf_ = *(const bf16x8*)&Wp[((size_t)(nt * 16 + ks) * 64 + lane) * 8];
            acc[j] = __builtin_amdgcn_mfma_f32_16x16x32_bf16(af, bf_, acc[j], 0, 0, 0);
        }
    }

    // D-frag: row = hi*4+r4, col = c
    #pragma unroll
    for (int j = 0; j < 3; ++j) {
        const int nt = ng * 3 + j;
        #pragma unroll
        for (int r4 = 0; r4 < 4; ++r4) {
            const int rloc = rg * 16 + hi * 4 + r4;
            const unsigned short v = f2bf(acc[j][r4]);
            if (nt < 4)       Qo[(row0 + rloc) * 64 + nt * 16 + c] = v;
            else if (nt < 8)  kt[rloc][(nt - 4) * 16 + c] = v;
            else              vt[(nt - 8) * 16 + c][rloc] = v;
        }
    }
    __syncthreads();

    // fragment-pack K and V (one 16B entry per thread, coalesced stores)
    const int tloc = (int)(row0 & 4095);
    const long bb = row0 >> 12;
    const int ci  = tloc >> 6;
    const int f_  = (tloc >> 5) & 1;
    const int ks0 = (tloc >> 4) & 3;      // 0 or 2
    if (tid < 256) {
        const int kk = tid >> 6, l = tid & 63;
        const ushort8 val = *(const ushort8*)&kt[l & 31][kk * 16 + (l >> 5) * 8];
        *(ushort8*)&Kp[((((bb * 64 + ci) * 2 + f_) * 4 + kk) * 64 + l) * 8] = val;
    } else {
        const int e = tid - 256;
        const int ksl = e >> 7, ct = (e >> 6) & 1, l = e & 63;
        const ushort8 val = *(const ushort8*)&vt[ct * 32 + (l & 31)][ksl * 16 + (l >> 5) * 8];
        *(ushort8*)&Vp[((((bb * 64 + ci) * 4 + ks0 + ksl) * 2 + ct) * 64 + l) * 8] = val;
    }
}

// ---- Kernel 2: causal flash attention, swapped-operand 32x32 MFMA ----------
// 512 blocks (4 batches x 128 tiles of 32 q, CU-balanced) x 8 waves, 8-way
// split-K. All K/V fragment loads are lane-linear from packed Kp/Vp.
__global__ __launch_bounds__(512, 2) void attn_kernel(
    const unsigned short* __restrict__ Q, const unsigned short* __restrict__ Kp,
    const unsigned short* __restrict__ Vp, float* __restrict__ out)
{
    __shared__ float accbuf[8][32][64];   // 64 KB split-K merge
    __shared__ float mbuf[8][32], lbuf[8][32];
    __shared__ float scb[8][32];

    const int tid = threadIdx.x, w = tid >> 6, lane = tid & 63;
    const int c = lane & 31, h = lane >> 5;
    const int b = blockIdx.x & 3;
    const int u = blockIdx.x >> 2;
    const int t = (u < 64) ? (127 - u) : (u - 64);
    const int qb = t << 5;

    const unsigned short* __restrict__ Qb  = Q  + ((long)b * T_ + qb) * 64;
    const unsigned short* __restrict__ Kpb = Kp + (size_t)b * 64 * 8 * 512;
    const unsigned short* __restrict__ Vpb = Vp + (size_t)b * 64 * 8 * 512;

    // Q^T B-frags (once per block, scatter ok)
    bf16x8 qf[4];
    #pragma unroll
    for (int kk = 0; kk < 4; ++kk)
        qf[kk] = *(const bf16x8*)&Qb[(long)c * 64 + kk * 16 + h * 8];

    f32x16 acc[2];
    #pragma unroll
    for (int ct = 0; ct < 2; ++ct)
        #pragma unroll
        for (int j = 0; j < 16; ++j) acc[ct][j] = 0.f;
    float m = -1e30f, l = 0.f;

    const int nc = ((qb + 31) >> 6) + 1;

    bf16x8 kf[2][4];
    {
        const size_t cp = (w < nc) ? w : (nc - 1);
        #pragma unroll
        for (int f = 0; f < 2; ++f)
            #pragma unroll
            for (int kk = 0; kk < 4; ++kk)
                kf[f][kk] = *(const bf16x8*)&Kpb[(((cp * 2 + f) * 4 + kk) * 64 + lane) * 8];
    }

    for (int ci = w; ci < nc; ci += 8) {
        const long s0 = (long)ci << 6;

        bf16x8 vf[4][2];
        #pragma unroll
        for (int ks = 0; ks < 4; ++ks)
            #pragma unroll
            for (int ct = 0; ct < 2; ++ct)
                vf[ks][ct] = *(const bf16x8*)&Vpb[((((size_t)ci * 4 + ks) * 2 + ct) * 64 + lane) * 8];

        // S^T = K Q^T : D[row=key][col=q]
        f32x16 sf[2];
        #pragma unroll
        for (int f = 0; f < 2; ++f) {
            #pragma unroll
            for (int j = 0; j < 16; ++j) sf[f][j] = 0.f;
            #pragma unroll
            for (int kk = 0; kk < 4; ++kk)
                sf[f] = __builtin_amdgcn_mfma_f32_32x32x16_bf16(kf[f][kk], qf[kk], sf[f], 0, 0, 0);
        }

        // prefetch next chunk's K
        bf16x8 kn[2][4];
        {
            const int cin = ci + 8;
            const size_t cp = (cin < nc) ? cin : (nc - 1);
            #pragma unroll
            for (int f = 0; f < 2; ++f)
                #pragma unroll
                for (int kk = 0; kk < 4; ++kk)
                    kn[f][kk] = *(const bf16x8*)&Kpb[(((cp * 2 + f) * 4 + kk) * 64 + lane) * 8];
        }

        // causal mask: key = s0 + 32f + (r&3) + 8*(r>>2) + 4h ; q = qb + c
        if ((int)s0 + 63 > qb) {
            #pragma unroll
            for (int f = 0; f < 2; ++f)
                #pragma unroll
                for (int r = 0; r < 16; ++r) {
                    const int key = (int)s0 + f * 32 + ((r & 3) + 8 * (r >> 2)) + 4 * h;
                    if (key > qb + c) sf[f][r] = -1e30f;
                }
        }

        // ---- online softmax (exp2 domain) ----
        float pm = sf[0][0];
        #pragma unroll
        for (int f = 0; f < 2; ++f)
            #pragma unroll
            for (int r = 0; r < 16; ++r) pm = fmaxf(pm, sf[f][r]);
        pm = fmaxf(pm, __shfl_xor(pm, 32));

        float mn = m;
        if (__any(pm > m)) {               // exact skip: if no column grew, sc == 1
            mn = fmaxf(m, pm);
            const float sc = exp2f(m - mn);
            m = mn;
            l *= sc;
            if (h == 0) scb[w][c] = sc;
            asm volatile("s_waitcnt lgkmcnt(0)" ::: "memory");
            __builtin_amdgcn_sched_barrier(0);
            float scr[16];
            #pragma unroll
            for (int r = 0; r < 16; ++r)
                scr[r] = scb[w][((r & 3) + 8 * (r >> 2)) + 4 * h];
            #pragma unroll
            for (int ct = 0; ct < 2; ++ct)
                #pragma unroll
                for (int r = 0; r < 16; ++r) acc[ct][r] *= scr[r];
        }

        float rs = 0.f;
        #pragma unroll
        for (int f = 0; f < 2; ++f)
            #pragma unroll
            for (int r = 0; r < 16; ++r) {
                const float p = exp2f(sf[f][r] - mn);
                sf[f][r] = p;
                rs += p;
            }
        rs += __shfl_xor(rs, 32);
        l += rs;

        // ---- P -> bf16 A-frags via cvt_pk + permlane32_swap; then PV ----
        #pragma unroll
        for (int f = 0; f < 2; ++f) {
            unsigned w01 = cvtpk(sf[f][0], sf[f][1]);
            unsigned w23 = cvtpk(sf[f][2], sf[f][3]);
            unsigned w45 = cvtpk(sf[f][4], sf[f][5]);
            unsigned w67 = cvtpk(sf[f][6], sf[f][7]);
            pls(w01, w45); pls(w23, w67);
            union { unsigned uu[4]; bf16x8 v; } pa0, pa1;
            pa0.uu[0] = w01; pa0.uu[1] = w23; pa0.uu[2] = w45; pa0.uu[3] = w67;
            unsigned x01 = cvtpk(sf[f][8],  sf[f][9]);
            unsigned x23 = cvtpk(sf[f][10], sf[f][11]);
            unsigned x45 = cvtpk(sf[f][12], sf[f][13]);
            unsigned x67 = cvtpk(sf[f][14], sf[f][15]);
            pls(x01, x45); pls(x23, x67);
            pa1.uu[0] = x01; pa1.uu[1] = x23; pa1.uu[2] = x45; pa1.uu[3] = x67;
            #pragma unroll
            for (int ct = 0; ct < 2; ++ct) {
                acc[ct] = __builtin_amdgcn_mfma_f32_32x32x16_bf16(pa0.v, vf[2 * f][ct],     acc[ct], 0, 0, 0);
                acc[ct] = __builtin_amdgcn_mfma_f32_32x32x16_bf16(pa1.v, vf[2 * f + 1][ct], acc[ct], 0, 0, 0);
            }
        }

        #pragma unroll
        for (int f = 0; f < 2; ++f)
            #pragma unroll
            for (int kk = 0; kk < 4; ++kk) kf[f][kk] = kn[f][kk];
    }

    // ---- split-K merge across the 8 waves ----
    if (h == 0) { mbuf[w][c] = m; lbuf[w][c] = l; }
    #pragma unroll
    for (int ct = 0; ct < 2; ++ct)
        #pragma unroll
        for (int r = 0; r < 16; ++r)
            accbuf[w][((r & 3) + 8 * (r >> 2)) + 4 * h][ct * 32 + c] = acc[ct][r];
    __syncthreads();
    #pragma unroll
    for (int i = 0; i < 4; ++i) {
        const int e = tid + i * 512;
        const int q = e >> 6, d = e & 63;
        float ms = mbuf[0][q];
        #pragma unroll
        for (int wv = 1; wv < 8; ++wv) ms = fmaxf(ms, mbuf[wv][q]);
        float ls = 0.f, os = 0.f;
        #pragma unroll
        for (int wv = 0; wv < 8; ++wv) {
            const float e_ = exp2f(mbuf[wv][q] - ms);
            ls += lbuf[wv][q] * e_;
            os += accbuf[wv][q][d] * e_;
        }
        out[((long)b * T_ + qb + q) * 64 + d] = os / ls;
    }
}

extern "C" void kernel_launch(void* const* d_in, const int* in_sizes, int n_in,
                              void* d_out, int out_size, void* d_ws, size_t ws_size,
                              hipStream_t stream)
{
    const float* emb = (const float*)d_in[0];
    const float* Wq  = (const float*)d_in[1];
    const float* Wk  = (const float*)d_in[2];
    const float* Wv  = (const float*)d_in[3];
    float* out = (float*)d_out;

    unsigned short* Qs = (unsigned short*)d_ws;         // 2 MB
    unsigned short* Kp = Qs + (size_t)B_ * T_ * A_;     // 2 MB packed K frags
    unsigned short* Vp = Kp + (size_t)B_ * T_ * A_;     // 2 MB packed V frags
    unsigned short* Wp = Vp + (size_t)B_ * T_ * A_;     // 192 KB packed W frags

    prep_w<<<dim3(48), dim3(256), 0, stream>>>(Wq, Wk, Wv, Wp);
    qkv_proj_kernel<<<dim3(512), dim3(512), 0, stream>>>(emb, Wp, Qs, Kp, Vp);
    attn_kernel<<<dim3(512), dim3(512), 0, stream>>>(Qs, Kp, Vp, out);
}